// Round 8
// baseline (108.621 us; speedup 1.0000x reference)
//
#include <hip/hip_runtime.h>
#include <hip/hip_bf16.h>

// Bilinear CNN pooling: dotted[b,c,d] = sum_x L[b,x,c]*R[b,x,d]  (B=32, X=12544, C=128)
// then signed-sqrt + global L2-normalize per batch.
//
// Round 8: barrier-free, LDS-free GEMM. Each wave gathers its MFMA fragments
// directly from global (L1/L2 serves the 3x cross-wave redundancy), splits
// f32 -> bf16 hi/lo in registers, 3-deep register prefetch, no syncs at all.

#define NK      8             // K-chunks per batch
#define KC      1568          // 12544 / 8
#define KSTEP   16            // k-rows per step
#define NT      98            // KC / KSTEP
#define BATCH   32
#define CDIM    128
#define XDIM    12544

typedef __bf16 bf16x8 __attribute__((ext_vector_type(8)));
typedef float  f32x16 __attribute__((ext_vector_type(16)));

// 16 MB partial buffer + per-segment sumsq; fully rewritten before read each launch.
__device__ float g_part[(size_t)NK * BATCH * CDIM * CDIM];
__device__ float g_ssq[BATCH * 16];

// Split 8 f32 -> RNE-bf16 hi + trunc-bf16 lo, packed into uint4s (validated r1-r7).
__device__ __forceinline__ void split8(const float* f, uint4& hi, uint4& lo) {
  uint xh[8], xl[8];
#pragma unroll
  for (int i = 0; i < 8; ++i) {
    uint u = __float_as_uint(f[i]);
    uint r = u + 0x7FFFu + ((u >> 16) & 1u);        // RNE bf16 in top 16 bits
    xh[i] = r;
    float hif = __uint_as_float(r & 0xFFFF0000u);    // exact hi value
    xl[i] = __float_as_uint(f[i] - hif);             // exact residual, trunc on pack
  }
  hi.x = __builtin_amdgcn_perm(xh[1], xh[0], 0x07060302u);
  hi.y = __builtin_amdgcn_perm(xh[3], xh[2], 0x07060302u);
  hi.z = __builtin_amdgcn_perm(xh[5], xh[4], 0x07060302u);
  hi.w = __builtin_amdgcn_perm(xh[7], xh[6], 0x07060302u);
  lo.x = __builtin_amdgcn_perm(xl[1], xl[0], 0x07060302u);
  lo.y = __builtin_amdgcn_perm(xl[3], xl[2], 0x07060302u);
  lo.z = __builtin_amdgcn_perm(xl[5], xl[4], 0x07060302u);
  lo.w = __builtin_amdgcn_perm(xl[7], xl[6], 0x07060302u);
}

// ---------------------------------------------------------------------------
// Kernel 1: per (chunk, batch): partial[c][d] = sum_{k in chunk} L[k][c]*R[k][d]
// 512 threads = 8 waves (2x4 grid of 64x32 output tiles, 32x32x16 MFMA,
// 3-pass hi/lo split). No LDS, no barriers: per-lane column gathers from
// global; k-step 16; 3 register parity sets (tile s -> set s%3).
// ---------------------------------------------------------------------------
__global__ __launch_bounds__(512, 2)
void bcnn_gemm_kernel(const float* __restrict__ L, const float* __restrict__ R) {
  const int chunk = blockIdx.x;      // 0..7
  const int b     = blockIdx.y;
  const int t     = threadIdx.x;
  const int l     = t & 63;
  const int w     = t >> 6;
  const int wr    = w >> 2;          // 0..1  (64-row block of C)
  const int wc    = w & 3;           // 0..3  (32-col block of C)
  const int lc    = l & 31;
  const int hh    = l >> 5;          // k-half: this lane holds k = s*16 + hh*8 + i

  // per-lane fragment columns
  const int cA0 = wr * 64 + lc;
  const int cA1 = cA0 + 32;
  const int cB  = wc * 32 + lc;

  const size_t base = ((size_t)b * XDIM + (size_t)chunk * KC + hh * 8) * CDIM;
  // prefetch cursors: always point at the NEXT step to load; advance by 16 rows
  const float* pA0 = L + base + cA0;
  const float* pA1 = L + base + cA1;
  const float* pB  = R + base + cB;
#define STEP_F (KSTEP * CDIM)

  f32x16 acc0 = {};
  f32x16 acc1 = {};

  // three static register parity sets
  float a0A[8], a1A[8], bA[8];
  float a0B[8], a1B[8], bB[8];
  float a0C[8], a1C[8], bC[8];

#define LOAD(a0, a1, bb)                                                        \
  do {                                                                          \
    _Pragma("unroll")                                                           \
    for (int i = 0; i < 8; ++i) {                                               \
      a0[i] = pA0[i * CDIM];                                                    \
      a1[i] = pA1[i * CDIM];                                                    \
      bb[i] = pB[i * CDIM];                                                     \
    }                                                                           \
    pA0 += STEP_F; pA1 += STEP_F; pB += STEP_F;                                 \
  } while (0)

// split current set, optionally refill it (prefetch s+3), then MFMA
#define STEP(a0, a1, bb, PF)                                                    \
  do {                                                                          \
    uint4 h0_, l0_, h1_, l1_, hb_, lb_;                                         \
    split8(a0, h0_, l0_);                                                       \
    split8(a1, h1_, l1_);                                                       \
    split8(bb, hb_, lb_);                                                       \
    if (PF) LOAD(a0, a1, bb);                                                   \
    bf16x8 ah0 = *(bf16x8*)&h0_, al0 = *(bf16x8*)&l0_;                          \
    bf16x8 ah1 = *(bf16x8*)&h1_, al1 = *(bf16x8*)&l1_;                          \
    bf16x8 bh  = *(bf16x8*)&hb_, bl  = *(bf16x8*)&lb_;                          \
    acc0 = __builtin_amdgcn_mfma_f32_32x32x16_bf16(ah0, bh, acc0, 0, 0, 0);     \
    acc1 = __builtin_amdgcn_mfma_f32_32x32x16_bf16(ah1, bh, acc1, 0, 0, 0);     \
    acc0 = __builtin_amdgcn_mfma_f32_32x32x16_bf16(ah0, bl, acc0, 0, 0, 0);     \
    acc1 = __builtin_amdgcn_mfma_f32_32x32x16_bf16(ah1, bl, acc1, 0, 0, 0);     \
    acc0 = __builtin_amdgcn_mfma_f32_32x32x16_bf16(al0, bh, acc0, 0, 0, 0);     \
    acc1 = __builtin_amdgcn_mfma_f32_32x32x16_bf16(al1, bh, acc1, 0, 0, 0);     \
  } while (0)

  // prologue: steps 0,1,2 in flight
  LOAD(a0A, a1A, bA);
  LOAD(a0B, a1B, bB);
  LOAD(a0C, a1C, bC);

  // main: 31 x 3 steps covering s = 0..92, prefetching s+3 = 3..95
  for (int it = 0; it < 31; ++it) {
    STEP(a0A, a1A, bA, 1);
    STEP(a0B, a1B, bB, 1);
    STEP(a0C, a1C, bC, 1);
  }
  // tail: s = 93..97 (prefetch 96, 97; then compute-only)
  STEP(a0A, a1A, bA, 1);   // s=93, pf 96 -> A
  STEP(a0B, a1B, bB, 1);   // s=94, pf 97 -> B
  STEP(a0C, a1C, bC, 0);   // s=95
  STEP(a0A, a1A, bA, 0);   // s=96
  STEP(a0B, a1B, bB, 0);   // s=97

#undef LOAD
#undef STEP
#undef STEP_F

  // C/D layout (HW-validated r1-r7): col = lane&31, row = (r&3)+8*(r>>2)+4*hh
  float* outp = g_part + (((size_t)chunk * BATCH + b) << 14);
#pragma unroll
  for (int r = 0; r < 16; ++r) {
    const int row = (r & 3) + ((r >> 2) << 3) + (hh << 2);
    outp[(size_t)(wr * 64 + row) * CDIM + (wc * 32 + lc)]      = acc0[r];
    outp[(size_t)(wr * 64 + 32 + row) * CDIM + (wc * 32 + lc)] = acc1[r];
  }
}

// ---------------------------------------------------------------------------
// Kernel 2a: sum NK partials, signed-sqrt, write sqrted, per-segment sumsq.
// ---------------------------------------------------------------------------
__global__ void bcnn_sqrt_kernel(float* __restrict__ out) {
  const int b   = blockIdx.y;
  const int seg = blockIdx.x;
  const int t   = threadIdx.x;
  const int idx = seg * 1024 + t * 4;

  float4 v = {0.f, 0.f, 0.f, 0.f};
#pragma unroll
  for (int ch = 0; ch < NK; ++ch) {
    const float4 p = *(const float4*)&g_part[(((size_t)ch * BATCH + b) << 14) + idx];
    v.x += p.x; v.y += p.y; v.z += p.z; v.w += p.w;
  }
  float4 sv;
  {
    float a;
    a = sqrtf(fabsf(v.x) + 1e-9f); sv.x = (v.x > 0.f) ? a : ((v.x < 0.f) ? -a : 0.f);
    a = sqrtf(fabsf(v.y) + 1e-9f); sv.y = (v.y > 0.f) ? a : ((v.y < 0.f) ? -a : 0.f);
    a = sqrtf(fabsf(v.z) + 1e-9f); sv.z = (v.z > 0.f) ? a : ((v.z < 0.f) ? -a : 0.f);
    a = sqrtf(fabsf(v.w) + 1e-9f); sv.w = (v.w > 0.f) ? a : ((v.w < 0.f) ? -a : 0.f);
  }
  *(float4*)&out[((size_t)b << 14) + idx] = sv;

  float ss = sv.x * sv.x + sv.y * sv.y + sv.z * sv.z + sv.w * sv.w;
#pragma unroll
  for (int o = 32; o > 0; o >>= 1) ss += __shfl_down(ss, o, 64);
  __shared__ float red[4];
  if ((t & 63) == 0) red[t >> 6] = ss;
  __syncthreads();
  if (t == 0) g_ssq[b * 16 + seg] = red[0] + red[1] + red[2] + red[3];
}

// ---------------------------------------------------------------------------
// Kernel 2b: scale by rsqrt(max(sumsq, 1e-12))
// ---------------------------------------------------------------------------
__global__ void bcnn_scale_kernel(float* __restrict__ out) {
  const int b   = blockIdx.y;
  const int seg = blockIdx.x;
  const int t   = threadIdx.x;

  float tot = 0.f;
#pragma unroll
  for (int i = 0; i < 16; ++i) tot += g_ssq[b * 16 + i];
  const float scale = rsqrtf(fmaxf(tot, 1e-12f));

  const size_t base = ((size_t)b << 14) + seg * 1024 + t * 4;
  float4 v = *(float4*)&out[base];
  v.x *= scale; v.y *= scale; v.z *= scale; v.w *= scale;
  *(float4*)&out[base] = v;
}

extern "C" void kernel_launch(void* const* d_in, const int* in_sizes, int n_in,
                              void* d_out, int out_size, void* d_ws, size_t ws_size,
                              hipStream_t stream) {
  const float* L = (const float*)d_in[0];
  const float* R = (const float*)d_in[1];
  float* out = (float*)d_out;

  dim3 g1(NK, BATCH);
  bcnn_gemm_kernel<<<g1, 512, 0, stream>>>(L, R);

  dim3 g2(16, BATCH);
  bcnn_sqrt_kernel<<<g2, 256, 0, stream>>>(out);
  bcnn_scale_kernel<<<g2, 256, 0, stream>>>(out);
}

// Round 9
// 88.989 us; speedup vs baseline: 1.2206x; 1.2206x over previous
//
#include <hip/hip_runtime.h>
#include <hip/hip_bf16.h>

// Bilinear CNN pooling: dotted[b,c,d] = sum_x L[b,x,c]*R[b,x,d]  (B=32, X=12544, C=128)
// then signed-sqrt + global L2-normalize per batch.
//
// Round 9: r6 pipeline (NK=8, BK=32, 3-deep lookahead, 64KB LDS, raw barriers)
// at DOUBLE occupancy: 1024 threads = 16 waves (4/SIMD), each wave a 32x32
// quadrant (6 MFMA + 8 ds_read_b128 per tile). Staging split4 per thread.

#define NK      8             // K-chunks per batch
#define KC      1568          // 12544 / 8
#define BK      32            // K per tile
#define NT      49            // KC / BK
#define BATCH   32
#define CDIM    128
#define XDIM    12544

typedef __bf16 bf16x8 __attribute__((ext_vector_type(8)));
typedef float  f32x16 __attribute__((ext_vector_type(16)));

// 16 MB partial buffer + per-segment sumsq; fully rewritten before read each launch.
__device__ float g_part[(size_t)NK * BATCH * CDIM * CDIM];
__device__ float g_ssq[BATCH * 16];

// Split 4 f32 -> RNE-bf16 hi + trunc-bf16 lo, packed into uint2s (validated r1-r8).
__device__ __forceinline__ void split4(const float* f, uint2& hi, uint2& lo) {
  uint xh[4], xl[4];
#pragma unroll
  for (int i = 0; i < 4; ++i) {
    uint u = __float_as_uint(f[i]);
    uint r = u + 0x7FFFu + ((u >> 16) & 1u);        // RNE bf16 in top 16 bits
    xh[i] = r;
    float hif = __uint_as_float(r & 0xFFFF0000u);    // exact hi value
    xl[i] = __float_as_uint(f[i] - hif);             // exact residual, trunc on pack
  }
  hi.x = __builtin_amdgcn_perm(xh[1], xh[0], 0x07060302u);
  hi.y = __builtin_amdgcn_perm(xh[3], xh[2], 0x07060302u);
  lo.x = __builtin_amdgcn_perm(xl[1], xl[0], 0x07060302u);
  lo.y = __builtin_amdgcn_perm(xl[3], xl[2], 0x07060302u);
}

// LDS 16B-unit index for (column c, k-half kh) within one 16-k substep (r4-r7 validated).
__device__ __forceinline__ int ldsu(int c, int kh) {
  return ((c << 1) | kh) ^ ((c >> 2) & 7);
}

// region base (in 16B uint4 units) for [set][sub][mat: 0=A,1=B][hilo]; 256 units each
#define REGN(set, sub, mat, hilo) ((((((set)*2 + (sub))*2 + (mat))*2) + (hilo)) * 256)

// ---------------------------------------------------------------------------
// Kernel 1: per (chunk, batch): partial[c][d] = sum_{k in chunk} L[k][c]*R[k][d]
// 1024 threads = 16 waves (4x4 grid of 32x32 output quadrants, 32x32x16 MFMA,
// 3-pass hi/lo split). LDS [set][sub][A/B][hi/lo][256]; 64 KB.
// ---------------------------------------------------------------------------
__global__ __launch_bounds__(1024, 4)
void bcnn_gemm_kernel(const float* __restrict__ L, const float* __restrict__ R) {
  __shared__ uint4 smem[4096];   // 64 KB

  const int chunk = blockIdx.x;      // 0..7
  const int b     = blockIdx.y;
  const int t     = threadIdx.x;
  const int l     = t & 63;
  const int w     = t >> 6;          // 0..15
  const int wr    = w >> 2;          // 0..3  (32-row quadrant)
  const int wc    = w & 3;           // 0..3  (32-col quadrant)
  const int lc    = l & 31;
  const int hh    = l >> 5;          // k-half within a 16-k substep

  // staging: thread owns column sc, k-rows sh*4 .. sh*4+3 of each 32-k tile
  const int sc   = t & 127;
  const int sh   = t >> 7;           // 0..7
  const int ssub = sh >> 2;          // 16-k substep this thread stages
  const int khs  = (sh >> 1) & 1;    // 8-k half within substep
  const int half = sh & 1;           // 4-elem (8B) half within the 16B unit
  const int wu   = ldsu(sc, khs);

  const float* gL = L + ((size_t)b * XDIM + (size_t)chunk * KC + sh * 4) * CDIM + sc;
  const float* gR = R + ((size_t)b * XDIM + (size_t)chunk * KC + sh * 4) * CDIM + sc;

  // fragment units (within a substep region)
  const int uA = ldsu(wr * 32 + lc, hh);
  const int uB = ldsu(wc * 32 + lc, hh);

  f32x16 acc = {};

  // three static register-parity sets (tile s -> parity s % 3)
  float rlA[4], rrA[4], rlB[4], rrB[4], rlC[4], rrC[4];

#define LOADR(rl, rr, s)                                                        \
  do {                                                                          \
    const float* pL_ = gL + (size_t)(s) * BK * CDIM;                            \
    const float* pR_ = gR + (size_t)(s) * BK * CDIM;                            \
    _Pragma("unroll")                                                           \
    for (int i = 0; i < 4; ++i) { rl[i] = pL_[i * CDIM]; rr[i] = pR_[i * CDIM]; } \
  } while (0)

#define WRITE(rl, rr, set)                                                      \
  do {                                                                          \
    uint2 hi_, lo_;                                                             \
    split4(rl, hi_, lo_);                                                       \
    ((uint2*)smem)[(REGN(set, ssub, 0, 0) + wu) * 2 + half] = hi_;              \
    ((uint2*)smem)[(REGN(set, ssub, 0, 1) + wu) * 2 + half] = lo_;              \
    split4(rr, hi_, lo_);                                                       \
    ((uint2*)smem)[(REGN(set, ssub, 1, 0) + wu) * 2 + half] = hi_;              \
    ((uint2*)smem)[(REGN(set, ssub, 1, 1) + wu) * 2 + half] = lo_;              \
  } while (0)

#define COMPUTE(set)                                                            \
  do {                                                                          \
    _Pragma("unroll")                                                           \
    for (int ss = 0; ss < 2; ++ss) {                                            \
      bf16x8 ah = *(const bf16x8*)&smem[REGN(set, ss, 0, 0) + uA];              \
      bf16x8 al = *(const bf16x8*)&smem[REGN(set, ss, 0, 1) + uA];              \
      bf16x8 bh = *(const bf16x8*)&smem[REGN(set, ss, 1, 0) + uB];              \
      bf16x8 bl = *(const bf16x8*)&smem[REGN(set, ss, 1, 1) + uB];              \
      acc = __builtin_amdgcn_mfma_f32_32x32x16_bf16(ah, bh, acc, 0, 0, 0);      \
      acc = __builtin_amdgcn_mfma_f32_32x32x16_bf16(ah, bl, acc, 0, 0, 0);      \
      acc = __builtin_amdgcn_mfma_f32_32x32x16_bf16(al, bh, acc, 0, 0, 0);      \
    }                                                                           \
  } while (0)

#define BAR()                                                                   \
  do {                                                                          \
    asm volatile("s_waitcnt lgkmcnt(0)" ::: "memory");                          \
    __builtin_amdgcn_s_barrier();                                               \
  } while (0)

  // prologue: tiles 0,1,2 in flight; write tile 0
  LOADR(rlA, rrA, 0);
  LOADR(rlB, rrB, 1);
  LOADR(rlC, rrC, 2);
  WRITE(rlA, rrA, 0);
  BAR();

  // steady state (r6-validated schedule): 6-unrolled, 3-deep lookahead
  for (int it = 0; it < 7; ++it) {
    const int s0 = 6 * it;
    /* s0+0 */ LOADR(rlA, rrA, s0 + 3); COMPUTE(0); WRITE(rlB, rrB, 1); BAR();
    /* s0+1 */ LOADR(rlB, rrB, s0 + 4); COMPUTE(1); WRITE(rlC, rrC, 0); BAR();
    /* s0+2 */ LOADR(rlC, rrC, s0 + 5); COMPUTE(0); WRITE(rlA, rrA, 1); BAR();
    /* s0+3 */ LOADR(rlA, rrA, s0 + 6); COMPUTE(1); WRITE(rlB, rrB, 0); BAR();
    /* s0+4 */ LOADR(rlB, rrB, s0 + 7); COMPUTE(0); WRITE(rlC, rrC, 1); BAR();
    /* s0+5 */ LOADR(rlC, rrC, s0 + 8); COMPUTE(1); WRITE(rlA, rrA, 0); BAR();
  }
  // peeled tail: s = 42..48 (loads stop at tile 48)
  /* s=42 */ LOADR(rlA, rrA, 45); COMPUTE(0); WRITE(rlB, rrB, 1); BAR();
  /* s=43 */ LOADR(rlB, rrB, 46); COMPUTE(1); WRITE(rlC, rrC, 0); BAR();
  /* s=44 */ LOADR(rlC, rrC, 47); COMPUTE(0); WRITE(rlA, rrA, 1); BAR();
  /* s=45 */ LOADR(rlA, rrA, 48); COMPUTE(1); WRITE(rlB, rrB, 0); BAR();
  /* s=46 */ COMPUTE(0); WRITE(rlC, rrC, 1); BAR();
  /* s=47 */ COMPUTE(1); WRITE(rlA, rrA, 0); BAR();
  /* s=48 */ COMPUTE(0);

#undef LOADR
#undef WRITE
#undef COMPUTE
#undef BAR

  // C/D layout (HW-validated r1-r8): col = lane&31, row = (r&3)+8*(r>>2)+4*hh
  // Each wave owns a disjoint 32x32 quadrant -> direct store, no merge.
  float* outp = g_part + (((size_t)chunk * BATCH + b) << 14);
#pragma unroll
  for (int r = 0; r < 16; ++r) {
    const int row = (r & 3) + ((r >> 2) << 3) + (hh << 2);
    outp[(size_t)(wr * 32 + row) * CDIM + (wc * 32 + lc)] = acc[r];
  }
}

// ---------------------------------------------------------------------------
// Kernel 2a: sum NK partials, signed-sqrt, write sqrted, per-segment sumsq.
// ---------------------------------------------------------------------------
__global__ void bcnn_sqrt_kernel(float* __restrict__ out) {
  const int b   = blockIdx.y;
  const int seg = blockIdx.x;
  const int t   = threadIdx.x;
  const int idx = seg * 1024 + t * 4;

  float4 v = {0.f, 0.f, 0.f, 0.f};
#pragma unroll
  for (int ch = 0; ch < NK; ++ch) {
    const float4 p = *(const float4*)&g_part[(((size_t)ch * BATCH + b) << 14) + idx];
    v.x += p.x; v.y += p.y; v.z += p.z; v.w += p.w;
  }
  float4 sv;
  {
    float a;
    a = sqrtf(fabsf(v.x) + 1e-9f); sv.x = (v.x > 0.f) ? a : ((v.x < 0.f) ? -a : 0.f);
    a = sqrtf(fabsf(v.y) + 1e-9f); sv.y = (v.y > 0.f) ? a : ((v.y < 0.f) ? -a : 0.f);
    a = sqrtf(fabsf(v.z) + 1e-9f); sv.z = (v.z > 0.f) ? a : ((v.z < 0.f) ? -a : 0.f);
    a = sqrtf(fabsf(v.w) + 1e-9f); sv.w = (v.w > 0.f) ? a : ((v.w < 0.f) ? -a : 0.f);
  }
  *(float4*)&out[((size_t)b << 14) + idx] = sv;

  float ss = sv.x * sv.x + sv.y * sv.y + sv.z * sv.z + sv.w * sv.w;
#pragma unroll
  for (int o = 32; o > 0; o >>= 1) ss += __shfl_down(ss, o, 64);
  __shared__ float red[4];
  if ((t & 63) == 0) red[t >> 6] = ss;
  __syncthreads();
  if (t == 0) g_ssq[b * 16 + seg] = red[0] + red[1] + red[2] + red[3];
}

// ---------------------------------------------------------------------------
// Kernel 2b: scale by rsqrt(max(sumsq, 1e-12))
// ---------------------------------------------------------------------------
__global__ void bcnn_scale_kernel(float* __restrict__ out) {
  const int b   = blockIdx.y;
  const int seg = blockIdx.x;
  const int t   = threadIdx.x;

  float tot = 0.f;
#pragma unroll
  for (int i = 0; i < 16; ++i) tot += g_ssq[b * 16 + i];
  const float scale = rsqrtf(fmaxf(tot, 1e-12f));

  const size_t base = ((size_t)b << 14) + seg * 1024 + t * 4;
  float4 v = *(float4*)&out[base];
  v.x *= scale; v.y *= scale; v.z *= scale; v.w *= scale;
  *(float4*)&out[base] = v;
}

extern "C" void kernel_launch(void* const* d_in, const int* in_sizes, int n_in,
                              void* d_out, int out_size, void* d_ws, size_t ws_size,
                              hipStream_t stream) {
  const float* L = (const float*)d_in[0];
  const float* R = (const float*)d_in[1];
  float* out = (float*)d_out;

  dim3 g1(NK, BATCH);
  bcnn_gemm_kernel<<<g1, 1024, 0, stream>>>(L, R);

  dim3 g2(16, BATCH);
  bcnn_sqrt_kernel<<<g2, 256, 0, stream>>>(out);
  bcnn_scale_kernel<<<g2, 256, 0, stream>>>(out);
}